// Round 13
// baseline (892.724 us; speedup 1.0000x reference)
//
#include <hip/hip_runtime.h>
#include <hip/hip_bf16.h>
#include <cmath>

using bf16   = __bf16;
using bf16x8 = __attribute__((ext_vector_type(8))) __bf16;
using bf16x4 = __attribute__((ext_vector_type(4))) __bf16;
using f32x4  = __attribute__((ext_vector_type(4))) float;
using u32x4  = __attribute__((ext_vector_type(4))) unsigned int;

// ------------------------------------------------------------------ prologue: casts + embedding
__global__ __launch_bounds__(256) void prologue_kernel(const int* __restrict__ idx,
                                                       const float* __restrict__ wte,
                                                       const float* __restrict__ wpe,
                                                       const float* __restrict__ c_attn_w,
                                                       const float* __restrict__ c_proj_w,
                                                       float* __restrict__ xf,
                                                       bf16* __restrict__ xb,
                                                       bf16* __restrict__ WqB,
                                                       bf16* __restrict__ WpB) {
  const int bid = blockIdx.x, tid = threadIdx.x;
  if (bid < 2048) {
    int t = bid & 1023;
    int tok = idx[bid];
    const float* wr = wte + (long)tok * 768;
    const float* pr = wpe + (long)t * 768;
    for (int c = tid; c < 768; c += 256) {
      float v = wr[c] + pr[c];
      xf[(long)bid * 768 + c] = v;
      xb[(long)bid * 768 + c] = (bf16)v;
    }
  }
  const int n4a = 4 * 2304 * 768 / 4;
  for (int i = bid * 256 + tid; i < n4a; i += 4096 * 256) {
    f32x4 v = ((const f32x4*)c_attn_w)[i];
    bf16x4 o;
    o[0] = (bf16)v[0]; o[1] = (bf16)v[1]; o[2] = (bf16)v[2]; o[3] = (bf16)v[3];
    ((bf16x4*)WqB)[i] = o;
  }
  const int n4p = 4 * 768 * 768 / 4;
  for (int i = bid * 256 + tid; i < n4p; i += 4096 * 256) {
    f32x4 v = ((const f32x4*)c_proj_w)[i];
    bf16x4 o;
    o[0] = (bf16)v[0]; o[1] = (bf16)v[1]; o[2] = (bf16)v[2]; o[3] = (bf16)v[3];
    ((bf16x4*)WpB)[i] = o;
  }
}

// ------------------------------------------------------------------ qkv GEMM with fused norm(ddof=1)+erf
__global__ __launch_bounds__(256) void gemmqkv_kernel(const bf16* __restrict__ A,
                                                      const bf16* __restrict__ W,
                                                      const float* __restrict__ eta_l,
                                                      bf16* __restrict__ qG,
                                                      bf16* __restrict__ aG,
                                                      bf16* __restrict__ bG,
                                                      float* __restrict__ vG) {
  __shared__ char ldsA[128 * 128];
  __shared__ char ldsB[128 * 128];
  const int tid = threadIdx.x;
  const int l = tid & 63, wid = tid >> 6;
  const int lr = l & 15, g = l >> 4;
  const int m0 = blockIdx.y * 128, n0 = blockIdx.x * 128;
  const int wm = wid >> 1, wn = wid & 1;
  const int K = 768;

  f32x4 acc[4][4];
#pragma unroll
  for (int i = 0; i < 4; ++i)
#pragma unroll
    for (int j = 0; j < 4; ++j) acc[i][j] = {0.f, 0.f, 0.f, 0.f};

  for (int k0 = 0; k0 < K; k0 += 32) {
    __syncthreads();
#pragma unroll
    for (int it = 0; it < 2; ++it) {
      int slot = tid + it * 256;
      int row = slot >> 2, q = slot & 3;
      u32x4 da = *(const u32x4*)(A + (long)(m0 + row) * K + k0 + q * 8);
      *(u32x4*)(ldsA + row * 128 + ((q * 16) ^ ((row & 7) << 4))) = da;
      u32x4 db = *(const u32x4*)(W + (long)(n0 + row) * K + k0 + q * 8);
      *(u32x4*)(ldsB + row * 128 + ((q * 16) ^ ((row & 7) << 4))) = db;
    }
    __syncthreads();
    bf16x8 af[4], bfr[4];
#pragma unroll
    for (int it = 0; it < 4; ++it) {
      int row = wm * 64 + it * 16 + lr;
      af[it] = *(const bf16x8*)(ldsA + row * 128 + ((16 * g) ^ ((row & 7) << 4)));
    }
#pragma unroll
    for (int jt = 0; jt < 4; ++jt) {
      int row = wn * 64 + jt * 16 + lr;
      bfr[jt] = *(const bf16x8*)(ldsB + row * 128 + ((16 * g) ^ ((row & 7) << 4)));
    }
#pragma unroll
    for (int it = 0; it < 4; ++it)
#pragma unroll
      for (int jt = 0; jt < 4; ++jt)
        acc[it][jt] = __builtin_amdgcn_mfma_f32_16x16x32_bf16(af[it], bfr[jt], acc[it][jt], 0, 0, 0);
  }

  const int gi = blockIdx.x * 2 + wn;     // 0..35 = s*12+h
  const int s = gi / 12, h = gi - s * 12;
  float evc[4];
#pragma unroll
  for (int jt = 0; jt < 4; ++jt) evc[jt] = eta_l[h * 64 + jt * 16 + lr];

#pragma unroll
  for (int it = 0; it < 4; ++it) {
#pragma unroll
    for (int r = 0; r < 4; ++r) {
      int row = m0 + wm * 64 + it * 16 + g * 4 + r;   // bt
      int b = row >> 10, t = row & 1023;
      float x0 = acc[it][0][r], x1 = acc[it][1][r];
      float x2 = acc[it][2][r], x3 = acc[it][3][r];
      float sum = (x0 + x1) + (x2 + x3);
#pragma unroll
      for (int o = 8; o; o >>= 1) sum += __shfl_xor(sum, o);
      float mu = sum * (1.f / 64.f);
      float d0 = x0 - mu, d1 = x1 - mu, d2 = x2 - mu, d3 = x3 - mu;
      float v2 = (d0 * d0 + d1 * d1) + (d2 * d2 + d3 * d3);
#pragma unroll
      for (int o = 8; o; o >>= 1) v2 += __shfl_xor(v2, o);
      float sd = sqrtf(v2 * (1.f / 63.f));
      float gn0 = d0 / sd, gn1 = d1 / sd, gn2 = d2 / sd, gn3 = d3 / sd;
      long base = ((long)(b * 12 + h) * 1024 + t) * 64 + lr;
      if (s == 0) {
        qG[base]      = (bf16)erff(gn0);
        qG[base + 16] = (bf16)erff(gn1);
        qG[base + 32] = (bf16)erff(gn2);
        qG[base + 48] = (bf16)erff(gn3);
      } else if (s == 1) {
        float k0 = erff(gn0), k1 = erff(gn1), k2 = erff(gn2), k3 = erff(gn3);
        aG[base]      = (bf16)(-k0);
        aG[base + 16] = (bf16)(-k1);
        aG[base + 32] = (bf16)(-k2);
        aG[base + 48] = (bf16)(-k3);
        bG[base]      = (bf16)(k0 * evc[0]);
        bG[base + 16] = (bf16)(k1 * evc[1]);
        bG[base + 32] = (bf16)(k2 * evc[2]);
        bG[base + 48] = (bf16)(k3 * evc[3]);
      } else {
        vG[base]      = gn0;
        vG[base + 16] = gn1;
        vG[base + 32] = gn2;
        vG[base + 48] = gn3;
      }
    }
  }
}

// ------------------------------------------------------------------ proj GEMM (residual add)
__global__ __launch_bounds__(256) void gemmproj_kernel(const bf16* __restrict__ A,
                                                       const bf16* __restrict__ W,
                                                       float* __restrict__ xf,
                                                       bf16* __restrict__ xb) {
  __shared__ char ldsA[128 * 128];
  __shared__ char ldsB[128 * 128];
  const int tid = threadIdx.x;
  const int l = tid & 63, wid = tid >> 6;
  const int lr = l & 15, g = l >> 4;
  const int m0 = blockIdx.y * 128, n0 = blockIdx.x * 128;
  const int wm = wid >> 1, wn = wid & 1;
  const int K = 768;

  f32x4 acc[4][4];
#pragma unroll
  for (int i = 0; i < 4; ++i)
#pragma unroll
    for (int j = 0; j < 4; ++j) acc[i][j] = {0.f, 0.f, 0.f, 0.f};

  for (int k0 = 0; k0 < K; k0 += 32) {
    __syncthreads();
#pragma unroll
    for (int it = 0; it < 2; ++it) {
      int slot = tid + it * 256;
      int row = slot >> 2, q = slot & 3;
      u32x4 da = *(const u32x4*)(A + (long)(m0 + row) * K + k0 + q * 8);
      *(u32x4*)(ldsA + row * 128 + ((q * 16) ^ ((row & 7) << 4))) = da;
      u32x4 db = *(const u32x4*)(W + (long)(n0 + row) * K + k0 + q * 8);
      *(u32x4*)(ldsB + row * 128 + ((q * 16) ^ ((row & 7) << 4))) = db;
    }
    __syncthreads();
    bf16x8 af[4], bfr[4];
#pragma unroll
    for (int it = 0; it < 4; ++it) {
      int row = wm * 64 + it * 16 + lr;
      af[it] = *(const bf16x8*)(ldsA + row * 128 + ((16 * g) ^ ((row & 7) << 4)));
    }
#pragma unroll
    for (int jt = 0; jt < 4; ++jt) {
      int row = wn * 64 + jt * 16 + lr;
      bfr[jt] = *(const bf16x8*)(ldsB + row * 128 + ((16 * g) ^ ((row & 7) << 4)));
    }
#pragma unroll
    for (int it = 0; it < 4; ++it)
#pragma unroll
      for (int jt = 0; jt < 4; ++jt)
        acc[it][jt] = __builtin_amdgcn_mfma_f32_16x16x32_bf16(af[it], bfr[jt], acc[it][jt], 0, 0, 0);
  }

#pragma unroll
  for (int it = 0; it < 4; ++it) {
#pragma unroll
    for (int jt = 0; jt < 4; ++jt) {
      int col = n0 + wn * 64 + jt * 16 + lr;
#pragma unroll
      for (int r = 0; r < 4; ++r) {
        int row = m0 + wm * 64 + it * 16 + g * 4 + r;
        long o = (long)row * 768 + col;
        float v = acc[it][jt][r] + xf[o];
        xf[o] = v;
        xb[o] = (bf16)v;
      }
    }
  }
}

// ------------------------------------------------------------------ grams per chunk (R1-verified)
__global__ __launch_bounds__(256) void gram_kernel(const bf16* __restrict__ aG,
                                                   const bf16* __restrict__ bG,
                                                   const bf16* __restrict__ qG,
                                                   float* __restrict__ GaG,
                                                   bf16* __restrict__ GqG,
                                                   bf16* __restrict__ bTG) {
  const int bh = blockIdx.x >> 6, ch = blockIdx.x & 63;
  __shared__ float as[16][68], bs[16][68], qs[16][68];
  const long tb = ((long)bh * 1024 + ch * 16) * 64;
  for (int i = threadIdx.x; i < 1024; i += 256) {
    int t = i >> 6, d = i & 63;
    as[t][d] = (float)aG[tb + i];
    bs[t][d] = (float)bG[tb + i];
    qs[t][d] = (float)qG[tb + i];
  }
  __syncthreads();
  const int t = threadIdx.x & 15, u = threadIdx.x >> 4;
  float dba = 0.f, dbq = 0.f;
#pragma unroll 4
  for (int d = 0; d < 64; ++d) {
    float bv = bs[u][d];
    dba += bv * as[t][d];
    dbq += bv * qs[t][d];
  }
  long g2 = (long)bh * 64 + ch;
  GaG[g2 * 256 + u * 16 + t] = (u < t) ? dba : 0.f;
  GqG[g2 * 512 + t * 32 + u] = (u <= t) ? (bf16)dbq : (bf16)0.f;
  GqG[g2 * 512 + t * 32 + 16 + u] = (bf16)0.f;
  int jj = threadIdx.x >> 2, uq = threadIdx.x & 3;
  bf16x8 pkv;
#pragma unroll
  for (int uu = 0; uu < 8; ++uu) pkv[uu] = (uq < 2) ? (bf16)bs[uq * 8 + uu][jj] : (bf16)0.f;
  *(bf16x8*)(bTG + g2 * 2048 + jj * 32 + uq * 8) = pkv;
}

// ------------------------------------------------------------------ chunked RWKV7 scan (R11 structure)
// one block per (b,h); 4 waves; pair-staged double buffering (1 barrier / 2 chunks).
// Explicit lgkmcnt fences REMOVED: sS/sM are wave-private, compiler-visible
// pointer accesses — conservative may-alias ordering + auto-waitcnt suffice,
// and removing sched_barrier lets the Ga/V load stream hoist under the MFMAs.
__global__ __launch_bounds__(256) void scan_kernel(const float* __restrict__ wdl,
                                                   const bf16* __restrict__ aG,
                                                   const bf16* __restrict__ qG,
                                                   const float* __restrict__ vG,
                                                   const float* __restrict__ GaG,
                                                   const bf16* __restrict__ GqG,
                                                   const bf16* __restrict__ bTG,
                                                   bf16* __restrict__ yG) {
  const int bh = blockIdx.x;
  const int b = bh / 12, h = bh - b * 12;
  const int tid = threadIdx.x;
  const int l = tid & 63, wid = tid >> 6;
  const int lr = l & 15, g = l >> 4;

  __shared__ char sA[2][2][16 * 128];
  __shared__ char sQ[2][2][16 * 128];
  __shared__ char sB[2][2][64 * 64];
  __shared__ char sG[2][2][16 * 64];
  __shared__ float sGa[2][2][16][16];
  __shared__ float sV[2][2][16][64];
  __shared__ char sS[64 * 128];
  __shared__ float sM[16][68];

  const float* wrow = wdl + h * 64;
  const int irow = wid * 16 + lr;
  const float w_rec = fmaxf(wrow[irow], 0.004f);
  const float winv = 1.0f / w_rec;

  float wc[4], w15c[4], l2wc[4];
#pragma unroll
  for (int r = 0; r < 4; ++r) {
    int row = wid * 16 + g * 4 + r;
    float w = fmaxf(wrow[row], 0.004f);
    wc[r] = w;
    l2wc[r] = log2f(w);
    w15c[r] = exp2f(15.0f * l2wc[r]);
  }

  f32x4 Sf[4];
#pragma unroll
  for (int j = 0; j < 4; ++j) Sf[j] = {0.f, 0.f, 0.f, 0.f};

  const long hTD = (long)bh * 65536;
  const long gB = (long)bh * 64;

  u32x4 rAQ[2], rB[2], rGG[2];
  f32x4 rV[2];

  auto LOAD2 = [&](int c0) {
#pragma unroll
    for (int k = 0; k < 2; ++k) {
      const int c = c0 + k;
      const long tb = hTD + (long)c * 1024;
      if (tid < 128) {
        rAQ[k] = *(const u32x4*)(aG + tb + (tid >> 3) * 64 + (tid & 7) * 8);
      } else {
        rAQ[k] = *(const u32x4*)(qG + tb + ((tid - 128) >> 3) * 64 + ((tid - 128) & 7) * 8);
      }
      rB[k] = *(const u32x4*)(bTG + (gB + c) * 2048 + (tid >> 2) * 32 + (tid & 3) * 8);
      if (tid < 64) {
        rGG[k] = *(const u32x4*)(GqG + (gB + c) * 512 + (tid >> 2) * 32 + (tid & 3) * 8);
      } else if (tid < 128) {
        rGG[k] = *(const u32x4*)(GaG + (gB + c) * 256 + ((tid - 64) >> 2) * 16 + ((tid - 64) & 3) * 4);
      }
      rV[k] = *(const f32x4*)(vG + tb + (tid >> 4) * 64 + (tid & 15) * 4);
    }
  };

  auto STORE2 = [&](int nb) {
#pragma unroll
    for (int k = 0; k < 2; ++k) {
      if (tid < 128) {
        int t = tid >> 3, q = tid & 7;
        *(u32x4*)(sA[nb][k] + t * 128 + ((q * 16) ^ ((t & 7) << 4))) = rAQ[k];
      } else {
        int t = (tid - 128) >> 3, q = (tid - 128) & 7;
        *(u32x4*)(sQ[nb][k] + t * 128 + ((q * 16) ^ ((t & 7) << 4))) = rAQ[k];
      }
      {
        int j = tid >> 2, q = tid & 3;
        *(u32x4*)(sB[nb][k] + j * 64 + ((q * 16) ^ ((j & 3) << 4))) = rB[k];
      }
      if (tid < 64) {
        int t = tid >> 2, q = tid & 3;
        *(u32x4*)(sG[nb][k] + t * 64 + ((q * 16) ^ ((t & 3) << 4))) = rGG[k];
      } else if (tid < 128) {
        int u = (tid - 64) >> 2, q = (tid - 64) & 3;
        *(u32x4*)(&sGa[nb][k][u][q * 4]) = rGG[k];
      }
      {
        int t = tid >> 4, i4 = tid & 15;
        *(f32x4*)(&sV[nb][k][t][i4 * 4]) = rV[k];
      }
    }
  };

  auto COMPUTE = [&](int cur, int cip, int ch) {
    const char* pA = sA[cur][cip];
    const char* pQ = sQ[cur][cip];
    const char* pB = sB[cur][cip];
    const char* pG = sG[cur][cip];
    const float* pGa = &sGa[cur][cip][0][0];
    const float* pV = &sV[cur][cip][0][0] + irow;
    const float* pM = &sM[0][0] + irow;

    f32x4 mf = {0.f, 0.f, 0.f, 0.f}, mqf = {0.f, 0.f, 0.f, 0.f};
#pragma unroll
    for (int s = 0; s < 2; ++s) {
      bf16x8 af = *(const bf16x8*)(sS + irow * 128 + ((64 * s + 16 * g) ^ ((irow & 7) << 4)));
      bf16x8 ba = *(const bf16x8*)(pA + lr * 128 + ((64 * s + 16 * g) ^ ((lr & 7) << 4)));
      bf16x8 bq = *(const bf16x8*)(pQ + lr * 128 + ((64 * s + 16 * g) ^ ((lr & 7) << 4)));
      mf = __builtin_amdgcn_mfma_f32_16x16x32_bf16(af, ba, mf, 0, 0, 0);
      mqf = __builtin_amdgcn_mfma_f32_16x16x32_bf16(af, bq, mqf, 0, 0, 0);
    }
#pragma unroll
    for (int r = 0; r < 4; ++r) sM[lr][wid * 16 + g * 4 + r] = mf[r];

    f32x4 acc4[4];
#pragma unroll
    for (int t = 0; t < 4; ++t) acc4[t] = {0.f, 0.f, 0.f, 0.f};
    bf16x8 zfrag;
#pragma unroll
    for (int i = 0; i < 8; ++i) zfrag[i] = (bf16)0.0f;
    float wp = 1.f, wpm1 = 0.f, wiv = 1.f;
#pragma unroll
    for (int u = 0; u < 16; ++u) {
      float muv = pM[u * 68];
      float vu = pV[u * 64];
      float cc = wp * muv + wpm1 * acc4[u >> 2][u & 3];
      float zt = wiv * (cc + vu);
      zfrag[u & 7] = (g == (u >> 3)) ? (bf16)zt : zfrag[u & 7];
      f32x4 ztv = {zt, zt, zt, zt};
#pragma unroll
      for (int qq = 0; qq < 4; ++qq) {
        f32x4 ga = *(const f32x4*)(pGa + u * 16 + qq * 4);
        acc4[qq] = __builtin_elementwise_fma(ga, ztv, acc4[qq]);
      }
      wpm1 = wp;
      wp *= w_rec;
      wiv *= winv;
    }

#pragma unroll
    for (int jt = 0; jt < 4; ++jt) {
      int jrow = jt * 16 + lr;
      bf16x8 bb = *(const bf16x8*)(pB + jrow * 64 + ((16 * g) ^ ((jrow & 3) << 4)));
      f32x4 cs;
#pragma unroll
      for (int r = 0; r < 4; ++r) cs[r] = Sf[jt][r] * wc[r];
      f32x4 ns = __builtin_amdgcn_mfma_f32_16x16x32_bf16(zfrag, bb, cs, 0, 0, 0);
#pragma unroll
      for (int r = 0; r < 4; ++r) Sf[jt][r] = ns[r] * w15c[r];
    }

#pragma unroll
    for (int jt = 0; jt < 4; ++jt) {
#pragma unroll
      for (int r = 0; r < 4; ++r) {
        int row = wid * 16 + g * 4 + r;
        int d = jt * 16 + lr;
        *(bf16*)(sS + row * 128 + ((d * 2) ^ ((row & 7) << 4))) = (bf16)Sf[jt][r];
      }
    }

    {
      bf16x8 gq = *(const bf16x8*)(pG + lr * 64 + ((16 * g) ^ ((lr & 3) << 4)));
      f32x4 cy;
#pragma unroll
      for (int r = 0; r < 4; ++r) cy[r] = mqf[r] * wc[r];
      f32x4 yp = __builtin_amdgcn_mfma_f32_16x16x32_bf16(zfrag, gq, cy, 0, 0, 0);
      bf16x4 yo;
#pragma unroll
      for (int r = 0; r < 4; ++r) yo[r] = (bf16)(yp[r] * exp2f((float)lr * l2wc[r]));
      long yoff = ((long)b * 1024 + ch * 16 + lr) * 768 + h * 64 + wid * 16 + g * 4;
      *(bf16x4*)(yG + yoff) = yo;
    }
  };

  LOAD2(0);
  STORE2(0);
#pragma unroll
  for (int jt = 0; jt < 4; ++jt) {
#pragma unroll
    for (int r = 0; r < 4; ++r) {
      int row = wid * 16 + g * 4 + r;
      int d = jt * 16 + lr;
      *(bf16*)(sS + row * 128 + ((d * 2) ^ ((row & 7) << 4))) = (bf16)0.0f;
    }
  }
  __syncthreads();

  for (int gp = 0; gp < 32; ++gp) {
    const int cur = gp & 1;
    if (gp < 31) LOAD2(2 * gp + 2);
    COMPUTE(cur, 0, 2 * gp);
    COMPUTE(cur, 1, 2 * gp + 1);
    if (gp < 31) STORE2(cur ^ 1);
    __syncthreads();
  }
}

// ------------------------------------------------------------------ lm_head with fused final norm
__global__ __launch_bounds__(256) void lmhead_kernel(const float* __restrict__ W,
                                                     const float* __restrict__ xf,
                                                     float* __restrict__ out) {
  __shared__ float xn[2][768];
  __shared__ float red[4];
  const int tid = threadIdx.x;
  for (int b = 0; b < 2; ++b) {
    const float* xr = xf + ((long)b * 1024 + 1023) * 768;
    float s = 0.f;
    for (int c = tid; c < 768; c += 256) s += xr[c];
#pragma unroll
    for (int o = 32; o; o >>= 1) s += __shfl_xor(s, o);
    if ((tid & 63) == 0) red[tid >> 6] = s;
    __syncthreads();
    float mu = (red[0] + red[1] + red[2] + red[3]) * (1.f / 768.f);
    __syncthreads();
    float s2 = 0.f;
    for (int c = tid; c < 768; c += 256) {
      float d = xr[c] - mu;
      s2 += d * d;
    }
#pragma unroll
    for (int o = 32; o; o >>= 1) s2 += __shfl_xor(s2, o);
    if ((tid & 63) == 0) red[tid >> 6] = s2;
    __syncthreads();
    float sd = sqrtf((red[0] + red[1] + red[2] + red[3]) * (1.f / 767.f));
    for (int c = tid; c < 768; c += 256) xn[b][c] = (xr[c] - mu) / sd;
    __syncthreads();
  }

  int l = tid & 63, wid = tid >> 6;
  int v0 = blockIdx.x * 64 + wid * 16;
  f32x4 x0[3], x1[3];
#pragma unroll
  for (int i = 0; i < 3; ++i) {
    x0[i] = *(const f32x4*)(&xn[0][l * 4 + i * 256]);
    x1[i] = *(const f32x4*)(&xn[1][l * 4 + i * 256]);
  }
  for (int vi = 0; vi < 16; ++vi) {
    const float* wr = W + (long)(v0 + vi) * 768;
    float pa = 0.f, pb = 0.f;
#pragma unroll
    for (int i = 0; i < 3; ++i) {
      f32x4 wv = *(const f32x4*)(wr + l * 4 + i * 256);
#pragma unroll
      for (int r = 0; r < 4; ++r) {
        pa += wv[r] * x0[i][r];
        pb += wv[r] * x1[i][r];
      }
    }
#pragma unroll
    for (int o = 32; o; o >>= 1) {
      pa += __shfl_xor(pa, o);
      pb += __shfl_xor(pb, o);
    }
    if (l == 0) {
      out[v0 + vi] = pa;
      out[50304 + v0 + vi] = pb;
    }
  }
}

// ------------------------------------------------------------------ host
extern "C" void kernel_launch(void* const* d_in, const int* in_sizes, int n_in,
                              void* d_out, int out_size, void* d_ws, size_t ws_size,
                              hipStream_t stream) {
  (void)in_sizes; (void)n_in; (void)out_size; (void)ws_size;
  const int*   idx      = (const int*)d_in[0];
  const float* wte      = (const float*)d_in[1];
  const float* wpe      = (const float*)d_in[2];
  const float* c_attn_w = (const float*)d_in[3];
  const float* c_proj_w = (const float*)d_in[4];
  const float* w_decay  = (const float*)d_in[5];
  const float* eta      = (const float*)d_in[6];
  const float* lm_head  = (const float*)d_in[7];
  float* out = (float*)d_out;

  char* ws = (char*)d_ws;
  size_t off = 0;
  auto alloc = [&](size_t bytes) -> char* {
    char* p = ws + off;
    off = (off + bytes + 255) & ~(size_t)255;
    return p;
  };
  float* xf   = (float*)alloc(2L * 1024 * 768 * 4);
  bf16*  xb   = (bf16*)alloc(2L * 1024 * 768 * 2);
  bf16*  qGp  = (bf16*)alloc(24L * 1024 * 64 * 2);
  bf16*  aGp  = (bf16*)alloc(24L * 1024 * 64 * 2);
  bf16*  bGp  = (bf16*)alloc(24L * 1024 * 64 * 2);
  float* vGp  = (float*)alloc(24L * 1024 * 64 * 4);
  float* GaGp = (float*)alloc(24L * 64 * 256 * 4);
  bf16*  GqGp = (bf16*)alloc(24L * 64 * 512 * 2);
  bf16*  bTGp = (bf16*)alloc(24L * 64 * 2048 * 2);
  bf16*  yGp  = (bf16*)alloc(2L * 1024 * 768 * 2);
  bf16*  WqB  = (bf16*)alloc(4L * 2304 * 768 * 2);
  bf16*  WpB  = (bf16*)alloc(4L * 768 * 768 * 2);

  prologue_kernel<<<dim3(4096), dim3(256), 0, stream>>>(
      idx, wte, wpe, c_attn_w, c_proj_w, xf, xb, WqB, WpB);

  for (int l = 0; l < 4; ++l) {
    gemmqkv_kernel<<<dim3(18, 16), dim3(256), 0, stream>>>(
        xb, WqB + (long)l * 2304 * 768, eta + l * 768, qGp, aGp, bGp, vGp);
    gram_kernel<<<dim3(1536), dim3(256), 0, stream>>>(aGp, bGp, qGp, GaGp, GqGp, bTGp);
    scan_kernel<<<dim3(24), dim3(256), 0, stream>>>(
        w_decay + l * 768, aGp, qGp, vGp, GaGp, GqGp, bTGp, yGp);
    gemmproj_kernel<<<dim3(6, 16), dim3(256), 0, stream>>>(
        yGp, WpB + (long)l * 768 * 768, xf, xb);
  }

  lmhead_kernel<<<dim3(786), dim3(256), 0, stream>>>(lm_head, xf, out);
}

// Round 14
// 765.936 us; speedup vs baseline: 1.1655x; 1.1655x over previous
//
#include <hip/hip_runtime.h>
#include <hip/hip_bf16.h>
#include <cmath>

using bf16   = __bf16;
using bf16x8 = __attribute__((ext_vector_type(8))) __bf16;
using bf16x4 = __attribute__((ext_vector_type(4))) __bf16;
using f32x4  = __attribute__((ext_vector_type(4))) float;
using u32x4  = __attribute__((ext_vector_type(4))) unsigned int;

// ------------------------------------------------------------------ prologue: casts + embedding
__global__ __launch_bounds__(256) void prologue_kernel(const int* __restrict__ idx,
                                                       const float* __restrict__ wte,
                                                       const float* __restrict__ wpe,
                                                       const float* __restrict__ c_attn_w,
                                                       const float* __restrict__ c_proj_w,
                                                       float* __restrict__ xf,
                                                       bf16* __restrict__ xb,
                                                       bf16* __restrict__ WqB,
                                                       bf16* __restrict__ WpB) {
  const int bid = blockIdx.x, tid = threadIdx.x;
  if (bid < 2048) {
    int t = bid & 1023;
    int tok = idx[bid];
    const float* wr = wte + (long)tok * 768;
    const float* pr = wpe + (long)t * 768;
    for (int c = tid; c < 768; c += 256) {
      float v = wr[c] + pr[c];
      xf[(long)bid * 768 + c] = v;
      xb[(long)bid * 768 + c] = (bf16)v;
    }
  }
  const int n4a = 4 * 2304 * 768 / 4;
  for (int i = bid * 256 + tid; i < n4a; i += 4096 * 256) {
    f32x4 v = ((const f32x4*)c_attn_w)[i];
    bf16x4 o;
    o[0] = (bf16)v[0]; o[1] = (bf16)v[1]; o[2] = (bf16)v[2]; o[3] = (bf16)v[3];
    ((bf16x4*)WqB)[i] = o;
  }
  const int n4p = 4 * 768 * 768 / 4;
  for (int i = bid * 256 + tid; i < n4p; i += 4096 * 256) {
    f32x4 v = ((const f32x4*)c_proj_w)[i];
    bf16x4 o;
    o[0] = (bf16)v[0]; o[1] = (bf16)v[1]; o[2] = (bf16)v[2]; o[3] = (bf16)v[3];
    ((bf16x4*)WpB)[i] = o;
  }
}

// ------------------------------------------------------------------ qkv GEMM with fused norm(ddof=1)+erf
// Double-buffered staging: LOAD(k+1)->regs, compute lds[cur], STORE->lds[nxt],
// one barrier per K-step (global latency hides under the 16-MFMA phase).
__global__ __launch_bounds__(256) void gemmqkv_kernel(const bf16* __restrict__ A,
                                                      const bf16* __restrict__ W,
                                                      const float* __restrict__ eta_l,
                                                      bf16* __restrict__ qG,
                                                      bf16* __restrict__ aG,
                                                      bf16* __restrict__ bG,
                                                      float* __restrict__ vG) {
  __shared__ char ldsA[2][128 * 128];
  __shared__ char ldsB[2][128 * 128];
  const int tid = threadIdx.x;
  const int l = tid & 63, wid = tid >> 6;
  const int lr = l & 15, g = l >> 4;
  const int m0 = blockIdx.y * 128, n0 = blockIdx.x * 128;
  const int wm = wid >> 1, wn = wid & 1;
  const int K = 768;

  f32x4 acc[4][4];
#pragma unroll
  for (int i = 0; i < 4; ++i)
#pragma unroll
    for (int j = 0; j < 4; ++j) acc[i][j] = {0.f, 0.f, 0.f, 0.f};

  u32x4 rA[2], rBv[2];
  auto LOADG = [&](int k0) {
#pragma unroll
    for (int it = 0; it < 2; ++it) {
      int slot = tid + it * 256;
      int row = slot >> 2, q = slot & 3;
      rA[it] = *(const u32x4*)(A + (long)(m0 + row) * K + k0 + q * 8);
      rBv[it] = *(const u32x4*)(W + (long)(n0 + row) * K + k0 + q * 8);
    }
  };
  auto STOREL = [&](int nb) {
#pragma unroll
    for (int it = 0; it < 2; ++it) {
      int slot = tid + it * 256;
      int row = slot >> 2, q = slot & 3;
      *(u32x4*)(ldsA[nb] + row * 128 + ((q * 16) ^ ((row & 7) << 4))) = rA[it];
      *(u32x4*)(ldsB[nb] + row * 128 + ((q * 16) ^ ((row & 7) << 4))) = rBv[it];
    }
  };

  LOADG(0);
  STOREL(0);
  __syncthreads();

  const int nk = K / 32;
  for (int kk = 0; kk < nk; ++kk) {
    const int cur = kk & 1;
    if (kk + 1 < nk) LOADG((kk + 1) * 32);
    bf16x8 af[4], bfr[4];
#pragma unroll
    for (int it = 0; it < 4; ++it) {
      int row = wm * 64 + it * 16 + lr;
      af[it] = *(const bf16x8*)(ldsA[cur] + row * 128 + ((16 * g) ^ ((row & 7) << 4)));
    }
#pragma unroll
    for (int jt = 0; jt < 4; ++jt) {
      int row = wn * 64 + jt * 16 + lr;
      bfr[jt] = *(const bf16x8*)(ldsB[cur] + row * 128 + ((16 * g) ^ ((row & 7) << 4)));
    }
#pragma unroll
    for (int it = 0; it < 4; ++it)
#pragma unroll
      for (int jt = 0; jt < 4; ++jt)
        acc[it][jt] = __builtin_amdgcn_mfma_f32_16x16x32_bf16(af[it], bfr[jt], acc[it][jt], 0, 0, 0);
    if (kk + 1 < nk) STOREL(cur ^ 1);
    __syncthreads();
  }

  const int gi = blockIdx.x * 2 + wn;     // 0..35 = s*12+h
  const int s = gi / 12, h = gi - s * 12;
  float evc[4];
#pragma unroll
  for (int jt = 0; jt < 4; ++jt) evc[jt] = eta_l[h * 64 + jt * 16 + lr];

#pragma unroll
  for (int it = 0; it < 4; ++it) {
#pragma unroll
    for (int r = 0; r < 4; ++r) {
      int row = m0 + wm * 64 + it * 16 + g * 4 + r;   // bt
      int b = row >> 10, t = row & 1023;
      float x0 = acc[it][0][r], x1 = acc[it][1][r];
      float x2 = acc[it][2][r], x3 = acc[it][3][r];
      float sum = (x0 + x1) + (x2 + x3);
#pragma unroll
      for (int o = 8; o; o >>= 1) sum += __shfl_xor(sum, o);
      float mu = sum * (1.f / 64.f);
      float d0 = x0 - mu, d1 = x1 - mu, d2 = x2 - mu, d3 = x3 - mu;
      float v2 = (d0 * d0 + d1 * d1) + (d2 * d2 + d3 * d3);
#pragma unroll
      for (int o = 8; o; o >>= 1) v2 += __shfl_xor(v2, o);
      float sd = sqrtf(v2 * (1.f / 63.f));
      float gn0 = d0 / sd, gn1 = d1 / sd, gn2 = d2 / sd, gn3 = d3 / sd;
      long base = ((long)(b * 12 + h) * 1024 + t) * 64 + lr;
      if (s == 0) {
        qG[base]      = (bf16)erff(gn0);
        qG[base + 16] = (bf16)erff(gn1);
        qG[base + 32] = (bf16)erff(gn2);
        qG[base + 48] = (bf16)erff(gn3);
      } else if (s == 1) {
        float k0 = erff(gn0), k1 = erff(gn1), k2 = erff(gn2), k3 = erff(gn3);
        aG[base]      = (bf16)(-k0);
        aG[base + 16] = (bf16)(-k1);
        aG[base + 32] = (bf16)(-k2);
        aG[base + 48] = (bf16)(-k3);
        bG[base]      = (bf16)(k0 * evc[0]);
        bG[base + 16] = (bf16)(k1 * evc[1]);
        bG[base + 32] = (bf16)(k2 * evc[2]);
        bG[base + 48] = (bf16)(k3 * evc[3]);
      } else {
        vG[base]      = gn0;
        vG[base + 16] = gn1;
        vG[base + 32] = gn2;
        vG[base + 48] = gn3;
      }
    }
  }
}

// ------------------------------------------------------------------ proj GEMM (residual add), double-buffered staging
__global__ __launch_bounds__(256) void gemmproj_kernel(const bf16* __restrict__ A,
                                                       const bf16* __restrict__ W,
                                                       float* __restrict__ xf,
                                                       bf16* __restrict__ xb) {
  __shared__ char ldsA[2][128 * 128];
  __shared__ char ldsB[2][128 * 128];
  const int tid = threadIdx.x;
  const int l = tid & 63, wid = tid >> 6;
  const int lr = l & 15, g = l >> 4;
  const int m0 = blockIdx.y * 128, n0 = blockIdx.x * 128;
  const int wm = wid >> 1, wn = wid & 1;
  const int K = 768;

  f32x4 acc[4][4];
#pragma unroll
  for (int i = 0; i < 4; ++i)
#pragma unroll
    for (int j = 0; j < 4; ++j) acc[i][j] = {0.f, 0.f, 0.f, 0.f};

  u32x4 rA[2], rBv[2];
  auto LOADG = [&](int k0) {
#pragma unroll
    for (int it = 0; it < 2; ++it) {
      int slot = tid + it * 256;
      int row = slot >> 2, q = slot & 3;
      rA[it] = *(const u32x4*)(A + (long)(m0 + row) * K + k0 + q * 8);
      rBv[it] = *(const u32x4*)(W + (long)(n0 + row) * K + k0 + q * 8);
    }
  };
  auto STOREL = [&](int nb) {
#pragma unroll
    for (int it = 0; it < 2; ++it) {
      int slot = tid + it * 256;
      int row = slot >> 2, q = slot & 3;
      *(u32x4*)(ldsA[nb] + row * 128 + ((q * 16) ^ ((row & 7) << 4))) = rA[it];
      *(u32x4*)(ldsB[nb] + row * 128 + ((q * 16) ^ ((row & 7) << 4))) = rBv[it];
    }
  };

  LOADG(0);
  STOREL(0);
  __syncthreads();

  const int nk = K / 32;
  for (int kk = 0; kk < nk; ++kk) {
    const int cur = kk & 1;
    if (kk + 1 < nk) LOADG((kk + 1) * 32);
    bf16x8 af[4], bfr[4];
#pragma unroll
    for (int it = 0; it < 4; ++it) {
      int row = wm * 64 + it * 16 + lr;
      af[it] = *(const bf16x8*)(ldsA[cur] + row * 128 + ((16 * g) ^ ((row & 7) << 4)));
    }
#pragma unroll
    for (int jt = 0; jt < 4; ++jt) {
      int row = wn * 64 + jt * 16 + lr;
      bfr[jt] = *(const bf16x8*)(ldsB[cur] + row * 128 + ((16 * g) ^ ((row & 7) << 4)));
    }
#pragma unroll
    for (int it = 0; it < 4; ++it)
#pragma unroll
      for (int jt = 0; jt < 4; ++jt)
        acc[it][jt] = __builtin_amdgcn_mfma_f32_16x16x32_bf16(af[it], bfr[jt], acc[it][jt], 0, 0, 0);
    if (kk + 1 < nk) STOREL(cur ^ 1);
    __syncthreads();
  }

#pragma unroll
  for (int it = 0; it < 4; ++it) {
#pragma unroll
    for (int jt = 0; jt < 4; ++jt) {
      int col = n0 + wn * 64 + jt * 16 + lr;
#pragma unroll
      for (int r = 0; r < 4; ++r) {
        int row = m0 + wm * 64 + it * 16 + g * 4 + r;
        long o = (long)row * 768 + col;
        float v = acc[it][jt][r] + xf[o];
        xf[o] = v;
        xb[o] = (bf16)v;
      }
    }
  }
}

// ------------------------------------------------------------------ grams per chunk (R1-verified)
__global__ __launch_bounds__(256) void gram_kernel(const bf16* __restrict__ aG,
                                                   const bf16* __restrict__ bG,
                                                   const bf16* __restrict__ qG,
                                                   float* __restrict__ GaG,
                                                   bf16* __restrict__ GqG,
                                                   bf16* __restrict__ bTG) {
  const int bh = blockIdx.x >> 6, ch = blockIdx.x & 63;
  __shared__ float as[16][68], bs[16][68], qs[16][68];
  const long tb = ((long)bh * 1024 + ch * 16) * 64;
  for (int i = threadIdx.x; i < 1024; i += 256) {
    int t = i >> 6, d = i & 63;
    as[t][d] = (float)aG[tb + i];
    bs[t][d] = (float)bG[tb + i];
    qs[t][d] = (float)qG[tb + i];
  }
  __syncthreads();
  const int t = threadIdx.x & 15, u = threadIdx.x >> 4;
  float dba = 0.f, dbq = 0.f;
#pragma unroll 4
  for (int d = 0; d < 64; ++d) {
    float bv = bs[u][d];
    dba += bv * as[t][d];
    dbq += bv * qs[t][d];
  }
  long g2 = (long)bh * 64 + ch;
  GaG[g2 * 256 + u * 16 + t] = (u < t) ? dba : 0.f;
  GqG[g2 * 512 + t * 32 + u] = (u <= t) ? (bf16)dbq : (bf16)0.f;
  GqG[g2 * 512 + t * 32 + 16 + u] = (bf16)0.f;
  int jj = threadIdx.x >> 2, uq = threadIdx.x & 3;
  bf16x8 pkv;
#pragma unroll
  for (int uu = 0; uu < 8; ++uu) pkv[uu] = (uq < 2) ? (bf16)bs[uq * 8 + uu][jj] : (bf16)0.f;
  *(bf16x8*)(bTG + g2 * 2048 + jj * 32 + uq * 8) = pkv;
}

// ------------------------------------------------------------------ chunked RWKV7 scan (R11-exact, 109.5us verified)
__global__ __launch_bounds__(256) void scan_kernel(const float* __restrict__ wdl,
                                                   const bf16* __restrict__ aG,
                                                   const bf16* __restrict__ qG,
                                                   const float* __restrict__ vG,
                                                   const float* __restrict__ GaG,
                                                   const bf16* __restrict__ GqG,
                                                   const bf16* __restrict__ bTG,
                                                   bf16* __restrict__ yG) {
  const int bh = blockIdx.x;
  const int b = bh / 12, h = bh - b * 12;
  const int tid = threadIdx.x;
  const int l = tid & 63, wid = tid >> 6;
  const int lr = l & 15, g = l >> 4;

  __shared__ char sA[2][2][16 * 128];
  __shared__ char sQ[2][2][16 * 128];
  __shared__ char sB[2][2][64 * 64];
  __shared__ char sG[2][2][16 * 64];
  __shared__ float sGa[2][2][16][16];
  __shared__ float sV[2][2][16][64];
  __shared__ char sS[64 * 128];
  __shared__ float sM[16][68];

  const float* wrow = wdl + h * 64;
  const int irow = wid * 16 + lr;
  const float w_rec = fmaxf(wrow[irow], 0.004f);
  const float winv = 1.0f / w_rec;

  float wc[4], w15c[4], l2wc[4];
#pragma unroll
  for (int r = 0; r < 4; ++r) {
    int row = wid * 16 + g * 4 + r;
    float w = fmaxf(wrow[row], 0.004f);
    wc[r] = w;
    l2wc[r] = log2f(w);
    w15c[r] = exp2f(15.0f * l2wc[r]);
  }

  f32x4 Sf[4];
#pragma unroll
  for (int j = 0; j < 4; ++j) Sf[j] = {0.f, 0.f, 0.f, 0.f};

  const long hTD = (long)bh * 65536;
  const long gB = (long)bh * 64;

  u32x4 rAQ[2], rB[2], rGG[2];
  f32x4 rV[2];

  auto LOAD2 = [&](int c0) {
#pragma unroll
    for (int k = 0; k < 2; ++k) {
      const int c = c0 + k;
      const long tb = hTD + (long)c * 1024;
      if (tid < 128) {
        rAQ[k] = *(const u32x4*)(aG + tb + (tid >> 3) * 64 + (tid & 7) * 8);
      } else {
        rAQ[k] = *(const u32x4*)(qG + tb + ((tid - 128) >> 3) * 64 + ((tid - 128) & 7) * 8);
      }
      rB[k] = *(const u32x4*)(bTG + (gB + c) * 2048 + (tid >> 2) * 32 + (tid & 3) * 8);
      if (tid < 64) {
        rGG[k] = *(const u32x4*)(GqG + (gB + c) * 512 + (tid >> 2) * 32 + (tid & 3) * 8);
      } else if (tid < 128) {
        rGG[k] = *(const u32x4*)(GaG + (gB + c) * 256 + ((tid - 64) >> 2) * 16 + ((tid - 64) & 3) * 4);
      }
      rV[k] = *(const f32x4*)(vG + tb + (tid >> 4) * 64 + (tid & 15) * 4);
    }
  };

  auto STORE2 = [&](int nb) {
#pragma unroll
    for (int k = 0; k < 2; ++k) {
      if (tid < 128) {
        int t = tid >> 3, q = tid & 7;
        *(u32x4*)(sA[nb][k] + t * 128 + ((q * 16) ^ ((t & 7) << 4))) = rAQ[k];
      } else {
        int t = (tid - 128) >> 3, q = (tid - 128) & 7;
        *(u32x4*)(sQ[nb][k] + t * 128 + ((q * 16) ^ ((t & 7) << 4))) = rAQ[k];
      }
      {
        int j = tid >> 2, q = tid & 3;
        *(u32x4*)(sB[nb][k] + j * 64 + ((q * 16) ^ ((j & 3) << 4))) = rB[k];
      }
      if (tid < 64) {
        int t = tid >> 2, q = tid & 3;
        *(u32x4*)(sG[nb][k] + t * 64 + ((q * 16) ^ ((t & 3) << 4))) = rGG[k];
      } else if (tid < 128) {
        int u = (tid - 64) >> 2, q = (tid - 64) & 3;
        *(u32x4*)(&sGa[nb][k][u][q * 4]) = rGG[k];
      }
      {
        int t = tid >> 4, i4 = tid & 15;
        *(f32x4*)(&sV[nb][k][t][i4 * 4]) = rV[k];
      }
    }
  };

  auto COMPUTE = [&](int cur, int cip, int ch) {
    const char* pA = sA[cur][cip];
    const char* pQ = sQ[cur][cip];
    const char* pB = sB[cur][cip];
    const char* pG = sG[cur][cip];
    const float* pGa = &sGa[cur][cip][0][0];
    const float* pV = &sV[cur][cip][0][0] + irow;
    const float* pM = &sM[0][0] + irow;

    asm volatile("s_waitcnt lgkmcnt(0)" ::: "memory");
    __builtin_amdgcn_sched_barrier(0);

    f32x4 mf = {0.f, 0.f, 0.f, 0.f}, mqf = {0.f, 0.f, 0.f, 0.f};
#pragma unroll
    for (int s = 0; s < 2; ++s) {
      bf16x8 af = *(const bf16x8*)(sS + irow * 128 + ((64 * s + 16 * g) ^ ((irow & 7) << 4)));
      bf16x8 ba = *(const bf16x8*)(pA + lr * 128 + ((64 * s + 16 * g) ^ ((lr & 7) << 4)));
      bf16x8 bq = *(const bf16x8*)(pQ + lr * 128 + ((64 * s + 16 * g) ^ ((lr & 7) << 4)));
      mf = __builtin_amdgcn_mfma_f32_16x16x32_bf16(af, ba, mf, 0, 0, 0);
      mqf = __builtin_amdgcn_mfma_f32_16x16x32_bf16(af, bq, mqf, 0, 0, 0);
    }
#pragma unroll
    for (int r = 0; r < 4; ++r) sM[lr][wid * 16 + g * 4 + r] = mf[r];
    asm volatile("s_waitcnt lgkmcnt(0)" ::: "memory");
    __builtin_amdgcn_sched_barrier(0);

    f32x4 acc4[4];
#pragma unroll
    for (int t = 0; t < 4; ++t) acc4[t] = {0.f, 0.f, 0.f, 0.f};
    bf16x8 zfrag;
#pragma unroll
    for (int i = 0; i < 8; ++i) zfrag[i] = (bf16)0.0f;
    float wp = 1.f, wpm1 = 0.f, wiv = 1.f;
#pragma unroll
    for (int u = 0; u < 16; ++u) {
      float muv = pM[u * 68];
      float vu = pV[u * 64];
      float cc = wp * muv + wpm1 * acc4[u >> 2][u & 3];
      float zt = wiv * (cc + vu);
      zfrag[u & 7] = (g == (u >> 3)) ? (bf16)zt : zfrag[u & 7];
      f32x4 ztv = {zt, zt, zt, zt};
#pragma unroll
      for (int qq = 0; qq < 4; ++qq) {
        f32x4 ga = *(const f32x4*)(pGa + u * 16 + qq * 4);
        acc4[qq] = __builtin_elementwise_fma(ga, ztv, acc4[qq]);
      }
      wpm1 = wp;
      wp *= w_rec;
      wiv *= winv;
    }

#pragma unroll
    for (int jt = 0; jt < 4; ++jt) {
      int jrow = jt * 16 + lr;
      bf16x8 bb = *(const bf16x8*)(pB + jrow * 64 + ((16 * g) ^ ((jrow & 3) << 4)));
      f32x4 cs;
#pragma unroll
      for (int r = 0; r < 4; ++r) cs[r] = Sf[jt][r] * wc[r];
      f32x4 ns = __builtin_amdgcn_mfma_f32_16x16x32_bf16(zfrag, bb, cs, 0, 0, 0);
#pragma unroll
      for (int r = 0; r < 4; ++r) Sf[jt][r] = ns[r] * w15c[r];
    }

#pragma unroll
    for (int jt = 0; jt < 4; ++jt) {
#pragma unroll
      for (int r = 0; r < 4; ++r) {
        int row = wid * 16 + g * 4 + r;
        int d = jt * 16 + lr;
        *(bf16*)(sS + row * 128 + ((d * 2) ^ ((row & 7) << 4))) = (bf16)Sf[jt][r];
      }
    }

    {
      bf16x8 gq = *(const bf16x8*)(pG + lr * 64 + ((16 * g) ^ ((lr & 3) << 4)));
      f32x4 cy;
#pragma unroll
      for (int r = 0; r < 4; ++r) cy[r] = mqf[r] * wc[r];
      f32x4 yp = __builtin_amdgcn_mfma_f32_16x16x32_bf16(zfrag, gq, cy, 0, 0, 0);
      bf16x4 yo;
#pragma unroll
      for (int r = 0; r < 4; ++r) yo[r] = (bf16)(yp[r] * exp2f((float)lr * l2wc[r]));
      long yoff = ((long)b * 1024 + ch * 16 + lr) * 768 + h * 64 + wid * 16 + g * 4;
      *(bf16x4*)(yG + yoff) = yo;
    }
  };

  LOAD2(0);
  STORE2(0);
#pragma unroll
  for (int jt = 0; jt < 4; ++jt) {
#pragma unroll
    for (int r = 0; r < 4; ++r) {
      int row = wid * 16 + g * 4 + r;
      int d = jt * 16 + lr;
      *(bf16*)(sS + row * 128 + ((d * 2) ^ ((row & 7) << 4))) = (bf16)0.0f;
    }
  }
  __syncthreads();

  for (int gp = 0; gp < 32; ++gp) {
    const int cur = gp & 1;
    if (gp < 31) LOAD2(2 * gp + 2);
    COMPUTE(cur, 0, 2 * gp);
    COMPUTE(cur, 1, 2 * gp + 1);
    if (gp < 31) STORE2(cur ^ 1);
    __syncthreads();
  }
}

// ------------------------------------------------------------------ lm_head with fused final norm
__global__ __launch_bounds__(256) void lmhead_kernel(const float* __restrict__ W,
                                                     const float* __restrict__ xf,
                                                     float* __restrict__ out) {
  __shared__ float xn[2][768];
  __shared__ float red[4];
  const int tid = threadIdx.x;
  for (int b = 0; b < 2; ++b) {
    const float* xr = xf + ((long)b * 1024 + 1023) * 768;
    float s = 0.f;
    for (int c = tid; c < 768; c += 256) s += xr[c];
#pragma unroll
    for (int o = 32; o; o >>= 1) s += __shfl_xor(s, o);
    if ((tid & 63) == 0) red[tid >> 6] = s;
    __syncthreads();
    float mu = (red[0] + red[1] + red[2] + red[3]) * (1.f / 768.f);
    __syncthreads();
    float s2 = 0.f;
    for (int c = tid; c < 768; c += 256) {
      float d = xr[c] - mu;
      s2 += d * d;
    }
#pragma unroll
    for (int o = 32; o; o >>= 1) s2 += __shfl_xor(s2, o);
    if ((tid & 63) == 0) red[tid >> 6] = s2;
    __syncthreads();
    float sd = sqrtf((red[0] + red[1] + red[2] + red[3]) * (1.f / 767.f));
    for (int c = tid; c < 768; c += 256) xn[b][c] = (xr[c] - mu) / sd;
    __syncthreads();
  }

  int l = tid & 63, wid = tid >> 6;
  int v0 = blockIdx.x * 64 + wid * 16;
  f32x4 x0[3], x1[3];
#pragma unroll
  for (int i = 0; i < 3; ++i) {
    x0[i] = *(const f32x4*)(&xn[0][l * 4 + i * 256]);
    x1[i] = *(const f32x4*)(&xn[1][l * 4 + i * 256]);
  }
  for (int vi = 0; vi < 16; ++vi) {
    const float* wr = W + (long)(v0 + vi) * 768;
    float pa = 0.f, pb = 0.f;
#pragma unroll
    for (int i = 0; i < 3; ++i) {
      f32x4 wv = *(const f32x4*)(wr + l * 4 + i * 256);
#pragma unroll
      for (int r = 0; r < 4; ++r) {
        pa += wv[r] * x0[i][r];
        pb += wv[r] * x1[i][r];
      }
    }
#pragma unroll
    for (int o = 32; o; o >>= 1) {
      pa += __shfl_xor(pa, o);
      pb += __shfl_xor(pb, o);
    }
    if (l == 0) {
      out[v0 + vi] = pa;
      out[50304 + v0 + vi] = pb;
    }
  }
}

// ------------------------------------------------------------------ host
extern "C" void kernel_launch(void* const* d_in, const int* in_sizes, int n_in,
                              void* d_out, int out_size, void* d_ws, size_t ws_size,
                              hipStream_t stream) {
  (void)in_sizes; (void)n_in; (void)out_size; (void)ws_size;
  const int*   idx      = (const int*)d_in[0];
  const float* wte      = (const float*)d_in[1];
  const float* wpe      = (const float*)d_in[2];
  const float* c_attn_w = (const float*)d_in[3];
  const float* c_proj_w = (const float*)d_in[4];
  const float* w_decay  = (const float*)d_in[5];
  const float* eta      = (const float*)d_in[6];
  const float* lm_head  = (const float*)d_in[7];
  float* out = (float*)d_out;

  char* ws = (char*)d_ws;
  size_t off = 0;
  auto alloc = [&](size_t bytes) -> char* {
    char* p = ws + off;
    off = (off + bytes + 255) & ~(size_t)255;
    return p;
  };
  float* xf   = (float*)alloc(2L * 1024 * 768 * 4);
  bf16*  xb   = (bf16*)alloc(2L * 1024 * 768 * 2);
  bf16*  qGp  = (bf16*)alloc(24L * 1024 * 64 * 2);
  bf16*  aGp  = (bf16*)alloc(24L * 1024 * 64 * 2);
  bf16*  bGp  = (bf16*)alloc(24L * 1024 * 64 * 2);
  float* vGp  = (float*)alloc(24L * 1024 * 64 * 4);
  float* GaGp = (float*)alloc(24L * 64 * 256 * 4);
  bf16*  GqGp = (bf16*)alloc(24L * 64 * 512 * 2);
  bf16*  bTGp = (bf16*)alloc(24L * 64 * 2048 * 2);
  bf16*  yGp  = (bf16*)alloc(2L * 1024 * 768 * 2);
  bf16*  WqB  = (bf16*)alloc(4L * 2304 * 768 * 2);
  bf16*  WpB  = (bf16*)alloc(4L * 768 * 768 * 2);

  prologue_kernel<<<dim3(4096), dim3(256), 0, stream>>>(
      idx, wte, wpe, c_attn_w, c_proj_w, xf, xb, WqB, WpB);

  for (int l = 0; l < 4; ++l) {
    gemmqkv_kernel<<<dim3(18, 16), dim3(256), 0, stream>>>(
        xb, WqB + (long)l * 2304 * 768, eta + l * 768, qGp, aGp, bGp, vGp);
    gram_kernel<<<dim3(1536), dim3(256), 0, stream>>>(aGp, bGp, qGp, GaGp, GqGp, bTGp);
    scan_kernel<<<dim3(24), dim3(256), 0, stream>>>(
        w_decay + l * 768, aGp, qGp, vGp, GaGp, GqGp, bTGp, yGp);
    gemmproj_kernel<<<dim3(6, 16), dim3(256), 0, stream>>>(
        yGp, WpB + (long)l * 768 * 768, xf, xb);
  }

  lmhead_kernel<<<dim3(786), dim3(256), 0, stream>>>(lm_head, xf, out);
}